// Round 4
// baseline (3004.441 us; speedup 1.0000x reference)
//
#include <hip/hip_runtime.h>
#include <hip/hip_bf16.h>

// B=16384, IN_DIM=4096, T=6, H=256. This round: ALL tensors treated as float32
// (per the reference's dtypes). Conservative constructs only (no MFMA, no
// builtins, no ext vectors) -- diagnostic round to establish execution + dtype.
//
// Pipeline:
//   precompute: qk[6][256] = tq . keyW, qb[6] = tq . keyb,
//               vbar[256] = mean_o valW[o][:], vbbar = mean(valb)
//   stage1 GEMM: h1[B][1536] = relu(x[B][4096] . headW1^T + headb1)
//   stage2 GEMM: h2[B][6][256] = relu(h1[:,t,:] . headW2[t]^T + headb2[t])
//   dots:  L[b][q][k] = (h2[b,k] . qk[q] + qb[q]) / 16
//          Vm[b][k]   =  h2[b,k] . vbar + vbbar
//   attn:  per b: softmax(eye + 0.1*L/(max+1e-8)) . Vm -> sigmoid -> clip -> out[B][6]
//
// ws layout (bytes), all float32:
//   [0,6144)    qk
//   [6144,7168) vbar
//   [7168,7200) qb
//   [7200,7204) vbbar
//   [8192, +100663296)              h1
//   [8192+100663296, +100663296)    h2
//   [8192+201326592, +2359296)      L
//   [8192+203685888, +393216)       Vm     (~204 MB total)

__global__ void M3H_64587718197825_kernel() {}

// C[M,N] = relu(A[M,K] * B[N,K]^T + bias[N]), f32.
// 128x128 tile, BK=8, 256 threads, 8x8 micro-tile per thread.
// grid.z batches tasks via per-z element offsets.
__global__ void gemm_f32(const float* A, const float* Bm, const float* bias, float* C,
                         int K, int lda, int ldb, int ldc,
                         long long aOffZ, long long bOffZ, long long cOffZ, long long biasOffZ)
{
    int z = blockIdx.z;
    A    += (long long)z * aOffZ;
    Bm   += (long long)z * bOffZ;
    C    += (long long)z * cOffZ;
    bias += (long long)z * biasOffZ;

    __shared__ float As[8][128];
    __shared__ float Bs[8][128];

    int tid = threadIdx.x;
    int tx = tid & 15, ty = tid >> 4;
    int tm = blockIdx.y * 128, tn = blockIdx.x * 128;

    float acc[8][8];
    for (int i = 0; i < 8; ++i)
        for (int j = 0; j < 8; ++j)
            acc[i][j] = 0.0f;

    int lr = tid >> 1;            // load row within tile: 0..127
    int lk = (tid & 1) * 4;       // k offset: 0 or 4
    const float* ag = A  + (long long)(tm + lr) * lda + lk;
    const float* bg = Bm + (long long)(tn + lr) * ldb + lk;

    for (int k0 = 0; k0 < K; k0 += 8) {
        float4 av = *(const float4*)(ag + k0);
        float4 bv = *(const float4*)(bg + k0);
        As[lk + 0][lr] = av.x; As[lk + 1][lr] = av.y;
        As[lk + 2][lr] = av.z; As[lk + 3][lr] = av.w;
        Bs[lk + 0][lr] = bv.x; Bs[lk + 1][lr] = bv.y;
        Bs[lk + 2][lr] = bv.z; Bs[lk + 3][lr] = bv.w;
        __syncthreads();
        for (int kk = 0; kk < 8; ++kk) {
            float a0[8], b0[8];
            for (int i = 0; i < 8; ++i) a0[i] = As[kk][ty * 8 + i];
            for (int j = 0; j < 8; ++j) b0[j] = Bs[kk][tx * 8 + j];
            for (int i = 0; i < 8; ++i)
                for (int j = 0; j < 8; ++j)
                    acc[i][j] += a0[i] * b0[j];
        }
        __syncthreads();
    }

    for (int i = 0; i < 8; ++i) {
        int row = tm + ty * 8 + i;
        float* cr = C + (long long)row * ldc;
        for (int j = 0; j < 8; ++j) {
            int col = tn + tx * 8 + j;
            float v = acc[i][j] + bias[col];
            cr[col] = v > 0.0f ? v : 0.0f;
        }
    }
}

// one block, 256 threads; thread h computes qk[q][h], vbar[h]
__global__ void precompute(const float* tq, const float* keyW, const float* keyb,
                           const float* valW, const float* valb,
                           float* qk, float* qb, float* vbar, float* vbbar)
{
    __shared__ float tqs[1536];
    int h = threadIdx.x;
    for (int i = h; i < 1536; i += 256) tqs[i] = tq[i];
    __syncthreads();
    float acc0 = 0.f, acc1 = 0.f, acc2 = 0.f, acc3 = 0.f, acc4 = 0.f, acc5 = 0.f;
    float vb = 0.f;
    for (int o = 0; o < 256; ++o) {
        float kw = keyW[o * 256 + h];
        float vw = valW[o * 256 + h];
        acc0 += tqs[0 * 256 + o] * kw;
        acc1 += tqs[1 * 256 + o] * kw;
        acc2 += tqs[2 * 256 + o] * kw;
        acc3 += tqs[3 * 256 + o] * kw;
        acc4 += tqs[4 * 256 + o] * kw;
        acc5 += tqs[5 * 256 + o] * kw;
        vb += vw;
    }
    qk[0 * 256 + h] = acc0;
    qk[1 * 256 + h] = acc1;
    qk[2 * 256 + h] = acc2;
    qk[3 * 256 + h] = acc3;
    qk[4 * 256 + h] = acc4;
    qk[5 * 256 + h] = acc5;
    vbar[h] = vb * (1.0f / 256.0f);
    if (h < 6) {
        float s = 0.f;
        for (int o = 0; o < 256; ++o) s += tq[h * 256 + o] * keyb[o];
        qb[h] = s;
    }
    if (h == 6) {
        float s = 0.f;
        for (int o = 0; o < 256; ++o) s += valb[o];
        vbbar[0] = s * (1.0f / 256.0f);
    }
}

// thread per row (b,k) of h2[B*6][256]: 7 dots with U = {qk[0..5], vbar}
__global__ void dots(const float* h2, const float* qk, const float* qb,
                     const float* vbar, const float* vbbar,
                     float* L, float* Vm)
{
    __shared__ float U[7][256];
    __shared__ float qbs[8];
    int tid = threadIdx.x;
    for (int i = tid; i < 1792; i += 256)
        U[i >> 8][i & 255] = (i < 1536) ? qk[i] : vbar[i & 255];
    if (tid < 6) qbs[tid] = qb[tid];
    if (tid == 6) qbs[6] = vbbar[0];
    __syncthreads();
    int row = blockIdx.x * 256 + tid;          // 98304 rows, 384 blocks exact
    const float* hr = h2 + (long long)row * 256;
    float a0 = 0.f, a1 = 0.f, a2 = 0.f, a3 = 0.f, a4 = 0.f, a5 = 0.f, a6 = 0.f;
    for (int i = 0; i < 256; i += 4) {
        float4 v = *(const float4*)(hr + i);
        float xs[4];
        xs[0] = v.x; xs[1] = v.y; xs[2] = v.z; xs[3] = v.w;
        for (int j = 0; j < 4; ++j) {
            float x = xs[j];
            int c = i + j;
            a0 += x * U[0][c];
            a1 += x * U[1][c];
            a2 += x * U[2][c];
            a3 += x * U[3][c];
            a4 += x * U[4][c];
            a5 += x * U[5][c];
            a6 += x * U[6][c];
        }
    }
    int b = row / 6, k = row - b * 6;
    float* Lr = L + (long long)b * 36 + k;
    Lr[0 * 6]  = (a0 + qbs[0]) * 0.0625f;
    Lr[1 * 6]  = (a1 + qbs[1]) * 0.0625f;
    Lr[2 * 6]  = (a2 + qbs[2]) * 0.0625f;
    Lr[3 * 6]  = (a3 + qbs[3]) * 0.0625f;
    Lr[4 * 6]  = (a4 + qbs[4]) * 0.0625f;
    Lr[5 * 6]  = (a5 + qbs[5]) * 0.0625f;
    Vm[row] = a6 + qbs[6];
}

// thread per b: 6x6 softmax + sigmoid + clip
__global__ void attn(const float* L, const float* Vm, const float* biasp, float* out)
{
    int b = blockIdx.x * 256 + threadIdx.x;    // 16384, 64 blocks exact
    float bias = biasp[0];
    float l[36], vm[6];
    const float* Lr = L + (long long)b * 36;
    for (int i = 0; i < 36; ++i) l[i] = Lr[i];
    for (int k = 0; k < 6; ++k) vm[k] = Vm[(long long)b * 6 + k];
    for (int q = 0; q < 6; ++q) {
        float m = l[q * 6];
        for (int k = 1; k < 6; ++k) m = fmaxf(m, l[q * 6 + k]);
        m += 1e-8f;
        float arg[6];
        float mx = -3.402823e38f;
        for (int k = 0; k < 6; ++k) {
            arg[k] = (k == q ? 1.0f : 0.0f) + 0.1f * l[q * 6 + k] / m;
            mx = fmaxf(mx, arg[k]);
        }
        float s = 0.f, y = 0.f;
        for (int k = 0; k < 6; ++k) {
            float e = expf(arg[k] - mx);
            s += e;
            y += e * vm[k];
        }
        y /= s;
        float p = 1.0f / (1.0f + expf(-(y - bias)));
        p = fminf(fmaxf(p, 1e-7f), 1.0f - 1e-7f);
        out[(long long)b * 6 + q] = p;
    }
}

extern "C" void kernel_launch(void* const* d_in, const int* in_sizes, int n_in,
                              void* d_out, int out_size, void* d_ws, size_t ws_size,
                              hipStream_t stream)
{
    const float* x      = (const float*)d_in[0];
    const float* headW1 = (const float*)d_in[1];
    const float* headb1 = (const float*)d_in[2];
    const float* headW2 = (const float*)d_in[3];
    const float* headb2 = (const float*)d_in[4];
    const float* tq     = (const float*)d_in[5];
    const float* keyW   = (const float*)d_in[6];
    const float* keyb   = (const float*)d_in[7];
    const float* valW   = (const float*)d_in[8];
    const float* valb   = (const float*)d_in[9];
    const float* biasp  = (const float*)d_in[10];
    float* out = (float*)d_out;

    char* w = (char*)d_ws;
    float* qk    = (float*)(w + 0);
    float* vbar  = (float*)(w + 6144);
    float* qb    = (float*)(w + 7168);
    float* vbbar = (float*)(w + 7200);
    float* h1    = (float*)(w + 8192);
    float* h2    = (float*)(w + 8192 + 100663296LL);
    float* L     = (float*)(w + 8192 + 2LL * 100663296LL);
    float* Vm    = (float*)(w + 8192 + 2LL * 100663296LL + 2359296LL);

    precompute<<<1, 256, 0, stream>>>(tq, keyW, keyb, valW, valb, qk, qb, vbar, vbbar);

    // stage1: M=16384 N=1536 K=4096; A=x (lda=4096), B=headW1 [1536][4096], C=h1 (ldc=1536)
    gemm_f32<<<dim3(12, 128, 1), 256, 0, stream>>>(
        x, headW1, headb1, h1, 4096, 4096, 4096, 1536, 0, 0, 0, 0);

    // stage2 (per task z): M=16384 N=256 K=256; A=h1+z*256 (lda=1536),
    // B=headW2[z] [256][256], C=h2+z*256 (ldc=1536, layout [B][6][256]), bias=headb2[z]
    gemm_f32<<<dim3(2, 128, 6), 256, 0, stream>>>(
        h1, headW2, headb2, h2, 256, 1536, 256, 1536, 256, 65536, 256, 256);

    dots<<<384, 256, 0, stream>>>(h2, qk, qb, vbar, vbbar, L, Vm);
    attn<<<64, 256, 0, stream>>>(L, Vm, biasp, out);
}